// Round 1
// baseline (636.550 us; speedup 1.0000x reference)
//
#include <hip/hip_runtime.h>

// GCN link predictor, fp32 end-to-end.
// Pipeline: CSR build (hist/scan/fill) -> [GEMM+dinv-scale -> CSR gather-agg]x2 -> pair-dot decode.
// norm factorization: h'[i] = dinv[i]*(x@W)[i];  z[i] = dinv[i]*(h'[i] + sum_{src->i} h'[src]) + b.

__global__ __launch_bounds__(256) void zero_i32(int* __restrict__ p, int n) {
    int i = blockIdx.x * blockDim.x + threadIdx.x;
    if (i < n) p[i] = 0;
}

__global__ __launch_bounds__(256) void hist_kernel(const int* __restrict__ dst,
                                                   int* __restrict__ counts, int E) {
    int e = blockIdx.x * blockDim.x + threadIdx.x;
    if (e < E) atomicAdd(&counts[dst[e]], 1);
}

// Single-block scan: counts (in) -> row_ptr, cursor (in-place over counts), dinv.
__global__ __launch_bounds__(256) void scan_kernel(int* __restrict__ counts_cursor,
                                                   int* __restrict__ row_ptr,
                                                   float* __restrict__ dinv, int N) {
    __shared__ int sums[256];
    int t = threadIdx.x;
    int chunk = (N + 255) >> 8;
    int lo = t * chunk, hi = min(lo + chunk, N);
    int s = 0;
    for (int i = lo; i < hi; ++i) s += counts_cursor[i];
    sums[t] = s;
    __syncthreads();
    if (t == 0) {
        int run = 0;
        for (int i = 0; i < 256; ++i) { int v = sums[i]; sums[i] = run; run += v; }
    }
    __syncthreads();
    int run = sums[t];
    for (int i = lo; i < hi; ++i) {
        int c = counts_cursor[i];
        row_ptr[i] = run;
        counts_cursor[i] = run;              // becomes the fill cursor
        dinv[i] = rsqrtf((float)(c + 1));    // +1 self-loop; deg >= 1 always
        run += c;
    }
    if (t == 255) row_ptr[N] = run;
}

__global__ __launch_bounds__(256) void fill_kernel(const int* __restrict__ src,
                                                   const int* __restrict__ dst,
                                                   int* __restrict__ cursor,
                                                   int* __restrict__ srcs_sorted, int E) {
    int e = blockIdx.x * blockDim.x + threadIdx.x;
    if (e < E) {
        int pos = atomicAdd(&cursor[dst[e]], 1);
        srcs_sorted[pos] = src[e];
    }
}

// H[r][c] = dinv[r] * sum_k X[r][k]*W[k][c].  W (128x128 fp32, 64 KB) staged in LDS.
// Block: 256 threads = 16 (tx: 8 cols each) x 16 (ty: 4 rows each) -> 64-row tile.
__global__ __launch_bounds__(256) void gemm_scale_kernel(const float* __restrict__ X,
                                                         const float* __restrict__ W,
                                                         const float* __restrict__ dinv,
                                                         float* __restrict__ H, int N) {
    __shared__ float Ws[128 * 128];
    float4* Ws4 = (float4*)Ws;
    const float4* W4 = (const float4*)W;
    for (int i = threadIdx.x; i < 128 * 32; i += 256) Ws4[i] = W4[i];
    __syncthreads();

    int tx = threadIdx.x & 15;
    int ty = threadIdx.x >> 4;
    int r0 = blockIdx.x * 64 + ty * 4;
    const float4* X4 = (const float4*)X;

    int rr[4];
#pragma unroll
    for (int i = 0; i < 4; ++i) rr[i] = min(r0 + i, N - 1);

    float4 acc[4][2];
#pragma unroll
    for (int i = 0; i < 4; ++i) {
        acc[i][0] = make_float4(0.f, 0.f, 0.f, 0.f);
        acc[i][1] = make_float4(0.f, 0.f, 0.f, 0.f);
    }

    float4 a_cur[4];
#pragma unroll
    for (int i = 0; i < 4; ++i) a_cur[i] = X4[rr[i] * 32];

    for (int kk = 0; kk < 128; kk += 4) {
        float4 a_nxt[4];
        bool more = (kk + 4 < 128);
        if (more) {
#pragma unroll
            for (int i = 0; i < 4; ++i) a_nxt[i] = X4[rr[i] * 32 + (kk >> 2) + 1];
        }
#pragma unroll
        for (int kin = 0; kin < 4; ++kin) {
            float4 w0 = Ws4[(kk + kin) * 32 + 2 * tx];
            float4 w1 = Ws4[(kk + kin) * 32 + 2 * tx + 1];
#pragma unroll
            for (int i = 0; i < 4; ++i) {
                float a = (kin == 0) ? a_cur[i].x : (kin == 1) ? a_cur[i].y
                        : (kin == 2) ? a_cur[i].z : a_cur[i].w;
                acc[i][0].x += a * w0.x; acc[i][0].y += a * w0.y;
                acc[i][0].z += a * w0.z; acc[i][0].w += a * w0.w;
                acc[i][1].x += a * w1.x; acc[i][1].y += a * w1.y;
                acc[i][1].z += a * w1.z; acc[i][1].w += a * w1.w;
            }
        }
        if (more) {
#pragma unroll
            for (int i = 0; i < 4; ++i) a_cur[i] = a_nxt[i];
        }
    }

    float4* H4 = (float4*)H;
#pragma unroll
    for (int i = 0; i < 4; ++i) {
        int r = r0 + i;
        if (r < N) {
            float di = dinv[r];
            float4 o0 = acc[i][0], o1 = acc[i][1];
            o0.x *= di; o0.y *= di; o0.z *= di; o0.w *= di;
            o1.x *= di; o1.y *= di; o1.z *= di; o1.w *= di;
            H4[r * 32 + 2 * tx] = o0;
            H4[r * 32 + 2 * tx + 1] = o1;
        }
    }
}

// One wave per node: z[i] = relu?( dinv[i]*(h'[i] + sum_{j in CSR(i)} h'[src_j]) + b ).
// Lane holds cols {2*lane, 2*lane+1} as float2 -> 512 B coalesced per gather.
__global__ __launch_bounds__(256) void agg_kernel(const float* __restrict__ Hp,
                                                  const int* __restrict__ row_ptr,
                                                  const int* __restrict__ srcs,
                                                  const float* __restrict__ dinv,
                                                  const float* __restrict__ bias,
                                                  float* __restrict__ Z, int N, int do_relu) {
    int gw = (int)((blockIdx.x * blockDim.x + threadIdx.x) >> 6);
    int lane = threadIdx.x & 63;
    if (gw >= N) return;
    const float2* H2 = (const float2*)Hp;
    float2 acc = H2[(size_t)gw * 64 + lane];  // self-loop term
    int beg = row_ptr[gw], end = row_ptr[gw + 1];
    for (int j = beg; j < end; ++j) {
        int s = srcs[j];
        float2 t = H2[(size_t)s * 64 + lane];
        acc.x += t.x; acc.y += t.y;
    }
    float di = dinv[gw];
    float2 bv = ((const float2*)bias)[lane];
    float ox = di * acc.x + bv.x;
    float oy = di * acc.y + bv.y;
    if (do_relu) { ox = fmaxf(ox, 0.f); oy = fmaxf(oy, 0.f); }
    ((float2*)Z)[(size_t)gw * 64 + lane] = make_float2(ox, oy);
}

// One wave per pair: out[p] = dot(z2[a], z2[b]) over 128 cols.
__global__ __launch_bounds__(256) void decode_kernel(const float* __restrict__ Z,
                                                     const int* __restrict__ pa,
                                                     const int* __restrict__ pb,
                                                     float* __restrict__ out, int P) {
    int gw = (int)((blockIdx.x * blockDim.x + threadIdx.x) >> 6);
    int lane = threadIdx.x & 63;
    if (gw >= P) return;
    int a = pa[gw], b = pb[gw];
    const float2* Z2 = (const float2*)Z;
    float2 va = Z2[(size_t)a * 64 + lane];
    float2 vb = Z2[(size_t)b * 64 + lane];
    float v = va.x * vb.x + va.y * vb.y;
#pragma unroll
    for (int off = 32; off > 0; off >>= 1) v += __shfl_down(v, off);
    if (lane == 0) out[gw] = v;
}

extern "C" void kernel_launch(void* const* d_in, const int* in_sizes, int n_in,
                              void* d_out, int out_size, void* d_ws, size_t ws_size,
                              hipStream_t stream) {
    const int*   edge_index = (const int*)d_in[0];
    const int*   edge_pairs = (const int*)d_in[1];
    const float* emb        = (const float*)d_in[2];
    const float* W1         = (const float*)d_in[3];
    const float* b1         = (const float*)d_in[4];
    const float* W2         = (const float*)d_in[5];
    const float* b2         = (const float*)d_in[6];
    float* out = (float*)d_out;

    int E = in_sizes[0] / 2;
    int P = in_sizes[1] / 2;
    int N = in_sizes[2] / 128;

    const int* src = edge_index;
    const int* dst = edge_index + E;
    const int* pa  = edge_pairs;
    const int* pb  = edge_pairs + P;

    // Workspace carve-up (all 256 B aligned): 2 big ping-pong buffers + CSR arrays.
    char* ws = (char*)d_ws;
    size_t off = 0;
    auto alloc = [&](size_t bytes) -> void* {
        void* p = ws + off;
        off = (off + bytes + 255) & ~(size_t)255;
        return p;
    };
    float* bufA        = (float*)alloc((size_t)N * 128 * sizeof(float)); // h'
    float* bufB        = (float*)alloc((size_t)N * 128 * sizeof(float)); // z
    int*   srcs_sorted = (int*)alloc((size_t)E * sizeof(int));
    int*   row_ptr     = (int*)alloc((size_t)(N + 1) * sizeof(int));
    int*   cursor      = (int*)alloc((size_t)N * sizeof(int));           // counts -> cursor
    float* dinv        = (float*)alloc((size_t)N * sizeof(float));

    // CSR build (per call; ws is re-poisoned before every launch)
    zero_i32<<<(N + 255) / 256, 256, 0, stream>>>(cursor, N);
    hist_kernel<<<(E + 255) / 256, 256, 0, stream>>>(dst, cursor, E);
    scan_kernel<<<1, 256, 0, stream>>>(cursor, row_ptr, dinv, N);
    fill_kernel<<<(E + 255) / 256, 256, 0, stream>>>(src, dst, cursor, srcs_sorted, E);

    // Layer 1: h1' = dinv*(emb@W1) -> agg+b1+relu -> z1 (bufB)
    gemm_scale_kernel<<<(N + 63) / 64, 256, 0, stream>>>(emb, W1, dinv, bufA, N);
    agg_kernel<<<(N + 3) / 4, 256, 0, stream>>>(bufA, row_ptr, srcs_sorted, dinv, b1, bufB, N, 1);

    // Layer 2: h2' = dinv*(z1@W2) -> agg+b2 -> z2 (bufB)
    gemm_scale_kernel<<<(N + 63) / 64, 256, 0, stream>>>(bufB, W2, dinv, bufA, N);
    agg_kernel<<<(N + 3) / 4, 256, 0, stream>>>(bufA, row_ptr, srcs_sorted, dinv, b2, bufB, N, 0);

    // Decode
    decode_kernel<<<(P + 3) / 4, 256, 0, stream>>>(bufB, pa, pb, out, P);
}

// Round 2
// 498.385 us; speedup vs baseline: 1.2772x; 1.2772x over previous
//
#include <hip/hip_runtime.h>

// GCN link predictor, fp32 end-to-end.
// Pipeline: CSR build (hist -> hierarchical scan -> fill) -> [GEMM+dinv-scale -> CSR gather-agg]x2
//           -> pair-dot decode.
// norm factorization: h'[i] = dinv[i]*(x@W)[i];  z[i] = dinv[i]*(h'[i] + sum_{src->i} h'[src]) + b.

__global__ __launch_bounds__(256) void zero_i32(int* __restrict__ p, int n) {
    int i = blockIdx.x * blockDim.x + threadIdx.x;
    if (i < n) p[i] = 0;
}

__global__ __launch_bounds__(256) void hist_kernel(const int* __restrict__ dst,
                                                   int* __restrict__ counts, int E) {
    int e = blockIdx.x * blockDim.x + threadIdx.x;
    if (e < E) atomicAdd(&counts[dst[e]], 1);
}

// --- hierarchical exclusive scan over counts[N] (R1's 1-block scan was 150us) ---

// Stage 1: per-block (256 elems) sum -> blk_sums[B]
__global__ __launch_bounds__(256) void scan_block_sums(const int* __restrict__ counts,
                                                       int* __restrict__ blk_sums, int N) {
    __shared__ int s[256];
    int t = threadIdx.x;
    int i = blockIdx.x * 256 + t;
    s[t] = (i < N) ? counts[i] : 0;
    __syncthreads();
#pragma unroll
    for (int off = 128; off > 0; off >>= 1) {
        if (t < off) s[t] += s[t + off];
        __syncthreads();
    }
    if (t == 0) blk_sums[blockIdx.x] = s[0];
}

// Stage 2: one block scans blk_sums (B <= 256) in place -> exclusive offsets
__global__ __launch_bounds__(256) void scan_offsets(int* __restrict__ blk_sums, int B) {
    __shared__ int s[2][256];
    int t = threadIdx.x;
    int v = (t < B) ? blk_sums[t] : 0;
    int cur = 0;
    s[0][t] = v;
    __syncthreads();
#pragma unroll
    for (int off = 1; off < 256; off <<= 1) {
        int nxt = cur ^ 1;
        int val = s[cur][t];
        if (t >= off) val += s[cur][t - off];
        s[nxt][t] = val;
        __syncthreads();
        cur = nxt;
    }
    if (t < B) blk_sums[t] = s[cur][t] - v;  // exclusive
}

// Stage 3: per-block inclusive scan + block offset -> row_ptr, cursor, dinv.
// Reads counts[i] before any write; cursor may alias counts.
__global__ __launch_bounds__(256) void scan_final(const int* __restrict__ counts,
                                                  const int* __restrict__ blk_off,
                                                  int* __restrict__ row_ptr,
                                                  int* __restrict__ cursor,
                                                  float* __restrict__ dinv, int N) {
    __shared__ int s[2][256];
    int t = threadIdx.x;
    int i = blockIdx.x * 256 + t;
    int c = (i < N) ? counts[i] : 0;
    int cur = 0;
    s[0][t] = c;
    __syncthreads();
#pragma unroll
    for (int off = 1; off < 256; off <<= 1) {
        int nxt = cur ^ 1;
        int val = s[cur][t];
        if (t >= off) val += s[cur][t - off];
        s[nxt][t] = val;
        __syncthreads();
        cur = nxt;
    }
    if (i < N) {
        int inc = s[cur][t] + blk_off[blockIdx.x];
        int exc = inc - c;
        row_ptr[i] = exc;
        cursor[i] = exc;
        dinv[i] = rsqrtf((float)(c + 1));  // +1 self-loop
        if (i == N - 1) row_ptr[N] = inc;
    }
}

__global__ __launch_bounds__(256) void fill_kernel(const int* __restrict__ src,
                                                   const int* __restrict__ dst,
                                                   int* __restrict__ cursor,
                                                   int* __restrict__ srcs_sorted, int E) {
    int e = blockIdx.x * blockDim.x + threadIdx.x;
    if (e < E) {
        int pos = atomicAdd(&cursor[dst[e]], 1);
        srcs_sorted[pos] = src[e];
    }
}

// H[r][c] = dinv[r] * sum_k X[r][k]*W[k][c].  W (128x128 fp32, 64 KB) staged in LDS.
// Block: 256 threads = 16 (tx: 8 cols each) x 16 (ty: 4 rows each) -> 64-row tile.
__global__ __launch_bounds__(256) void gemm_scale_kernel(const float* __restrict__ X,
                                                         const float* __restrict__ W,
                                                         const float* __restrict__ dinv,
                                                         float* __restrict__ H, int N) {
    __shared__ float Ws[128 * 128];
    float4* Ws4 = (float4*)Ws;
    const float4* W4 = (const float4*)W;
    for (int i = threadIdx.x; i < 128 * 32; i += 256) Ws4[i] = W4[i];
    __syncthreads();

    int tx = threadIdx.x & 15;
    int ty = threadIdx.x >> 4;
    int r0 = blockIdx.x * 64 + ty * 4;
    const float4* X4 = (const float4*)X;

    int rr[4];
#pragma unroll
    for (int i = 0; i < 4; ++i) rr[i] = min(r0 + i, N - 1);

    float4 acc[4][2];
#pragma unroll
    for (int i = 0; i < 4; ++i) {
        acc[i][0] = make_float4(0.f, 0.f, 0.f, 0.f);
        acc[i][1] = make_float4(0.f, 0.f, 0.f, 0.f);
    }

    float4 a_cur[4];
#pragma unroll
    for (int i = 0; i < 4; ++i) a_cur[i] = X4[rr[i] * 32];

    for (int kk = 0; kk < 128; kk += 4) {
        float4 a_nxt[4];
        bool more = (kk + 4 < 128);
        if (more) {
#pragma unroll
            for (int i = 0; i < 4; ++i) a_nxt[i] = X4[rr[i] * 32 + (kk >> 2) + 1];
        }
#pragma unroll
        for (int kin = 0; kin < 4; ++kin) {
            float4 w0 = Ws4[(kk + kin) * 32 + 2 * tx];
            float4 w1 = Ws4[(kk + kin) * 32 + 2 * tx + 1];
#pragma unroll
            for (int i = 0; i < 4; ++i) {
                float a = (kin == 0) ? a_cur[i].x : (kin == 1) ? a_cur[i].y
                        : (kin == 2) ? a_cur[i].z : a_cur[i].w;
                acc[i][0].x += a * w0.x; acc[i][0].y += a * w0.y;
                acc[i][0].z += a * w0.z; acc[i][0].w += a * w0.w;
                acc[i][1].x += a * w1.x; acc[i][1].y += a * w1.y;
                acc[i][1].z += a * w1.z; acc[i][1].w += a * w1.w;
            }
        }
        if (more) {
#pragma unroll
            for (int i = 0; i < 4; ++i) a_cur[i] = a_nxt[i];
        }
    }

    float4* H4 = (float4*)H;
#pragma unroll
    for (int i = 0; i < 4; ++i) {
        int r = r0 + i;
        if (r < N) {
            float di = dinv[r];
            float4 o0 = acc[i][0], o1 = acc[i][1];
            o0.x *= di; o0.y *= di; o0.z *= di; o0.w *= di;
            o1.x *= di; o1.y *= di; o1.z *= di; o1.w *= di;
            H4[r * 32 + 2 * tx] = o0;
            H4[r * 32 + 2 * tx + 1] = o1;
        }
    }
}

// One wave per node: z[i] = relu?( dinv[i]*(h'[i] + sum_{j in CSR(i)} h'[src_j]) + b ).
// Lane holds cols {2*lane, 2*lane+1} as float2 -> 512 B coalesced per gather.
__global__ __launch_bounds__(256) void agg_kernel(const float* __restrict__ Hp,
                                                  const int* __restrict__ row_ptr,
                                                  const int* __restrict__ srcs,
                                                  const float* __restrict__ dinv,
                                                  const float* __restrict__ bias,
                                                  float* __restrict__ Z, int N, int do_relu) {
    int gw = (int)((blockIdx.x * blockDim.x + threadIdx.x) >> 6);
    int lane = threadIdx.x & 63;
    if (gw >= N) return;
    const float2* H2 = (const float2*)Hp;
    float2 acc = H2[(size_t)gw * 64 + lane];  // self-loop term
    int beg = row_ptr[gw], end = row_ptr[gw + 1];
    for (int j = beg; j < end; ++j) {
        int s = srcs[j];
        float2 t = H2[(size_t)s * 64 + lane];
        acc.x += t.x; acc.y += t.y;
    }
    float di = dinv[gw];
    float2 bv = ((const float2*)bias)[lane];
    float ox = di * acc.x + bv.x;
    float oy = di * acc.y + bv.y;
    if (do_relu) { ox = fmaxf(ox, 0.f); oy = fmaxf(oy, 0.f); }
    ((float2*)Z)[(size_t)gw * 64 + lane] = make_float2(ox, oy);
}

// One wave per pair: out[p] = dot(z2[a], z2[b]) over 128 cols.
__global__ __launch_bounds__(256) void decode_kernel(const float* __restrict__ Z,
                                                     const int* __restrict__ pa,
                                                     const int* __restrict__ pb,
                                                     float* __restrict__ out, int P) {
    int gw = (int)((blockIdx.x * blockDim.x + threadIdx.x) >> 6);
    int lane = threadIdx.x & 63;
    if (gw >= P) return;
    int a = pa[gw], b = pb[gw];
    const float2* Z2 = (const float2*)Z;
    float2 va = Z2[(size_t)a * 64 + lane];
    float2 vb = Z2[(size_t)b * 64 + lane];
    float v = va.x * vb.x + va.y * vb.y;
#pragma unroll
    for (int off = 32; off > 0; off >>= 1) v += __shfl_down(v, off);
    if (lane == 0) out[gw] = v;
}

extern "C" void kernel_launch(void* const* d_in, const int* in_sizes, int n_in,
                              void* d_out, int out_size, void* d_ws, size_t ws_size,
                              hipStream_t stream) {
    const int*   edge_index = (const int*)d_in[0];
    const int*   edge_pairs = (const int*)d_in[1];
    const float* emb        = (const float*)d_in[2];
    const float* W1         = (const float*)d_in[3];
    const float* b1         = (const float*)d_in[4];
    const float* W2         = (const float*)d_in[5];
    const float* b2         = (const float*)d_in[6];
    float* out = (float*)d_out;

    int E = in_sizes[0] / 2;
    int P = in_sizes[1] / 2;
    int N = in_sizes[2] / 128;
    int B = (N + 255) / 256;  // scan blocks (196 for N=50000, must be <= 256)

    const int* src = edge_index;
    const int* dst = edge_index + E;
    const int* pa  = edge_pairs;
    const int* pb  = edge_pairs + P;

    // Workspace carve-up (all 256 B aligned).
    char* ws = (char*)d_ws;
    size_t off = 0;
    auto alloc = [&](size_t bytes) -> void* {
        void* p = ws + off;
        off = (off + bytes + 255) & ~(size_t)255;
        return p;
    };
    float* bufA        = (float*)alloc((size_t)N * 128 * sizeof(float)); // h'
    float* bufB        = (float*)alloc((size_t)N * 128 * sizeof(float)); // z
    int*   srcs_sorted = (int*)alloc((size_t)E * sizeof(int));
    int*   row_ptr     = (int*)alloc((size_t)(N + 1) * sizeof(int));
    int*   counts      = (int*)alloc((size_t)N * sizeof(int));           // counts -> cursor
    float* dinv        = (float*)alloc((size_t)N * sizeof(float));
    int*   blk_sums    = (int*)alloc((size_t)B * sizeof(int));

    // CSR build (per call; ws is re-poisoned before every launch)
    zero_i32<<<(N + 255) / 256, 256, 0, stream>>>(counts, N);
    hist_kernel<<<(E + 255) / 256, 256, 0, stream>>>(dst, counts, E);
    scan_block_sums<<<B, 256, 0, stream>>>(counts, blk_sums, N);
    scan_offsets<<<1, 256, 0, stream>>>(blk_sums, B);
    scan_final<<<B, 256, 0, stream>>>(counts, blk_sums, row_ptr, counts, dinv, N);
    fill_kernel<<<(E + 255) / 256, 256, 0, stream>>>(src, dst, counts, srcs_sorted, E);

    // Layer 1: h1' = dinv*(emb@W1) -> agg+b1+relu -> z1 (bufB)
    gemm_scale_kernel<<<(N + 63) / 64, 256, 0, stream>>>(emb, W1, dinv, bufA, N);
    agg_kernel<<<(N + 3) / 4, 256, 0, stream>>>(bufA, row_ptr, srcs_sorted, dinv, b1, bufB, N, 1);

    // Layer 2: h2' = dinv*(z1@W2) -> agg+b2 -> z2 (bufB)
    gemm_scale_kernel<<<(N + 63) / 64, 256, 0, stream>>>(bufB, W2, dinv, bufA, N);
    agg_kernel<<<(N + 3) / 4, 256, 0, stream>>>(bufA, row_ptr, srcs_sorted, dinv, b2, bufB, N, 0);

    // Decode
    decode_kernel<<<(P + 3) / 4, 256, 0, stream>>>(bufB, pa, pb, out, P);
}

// Round 3
// 418.013 us; speedup vs baseline: 1.5228x; 1.1923x over previous
//
#include <hip/hip_runtime.h>

// GCN link predictor, fp32 end-to-end.
// Pipeline: CSR build (hist -> hierarchical scan -> fill) -> [GEMM+dinv-scale -> CSR gather-agg]x2
//           -> pair-dot decode.
// norm factorization: h'[i] = dinv[i]*(x@W)[i];  z[i] = dinv[i]*(h'[i] + sum_{src->i} h'[src]) + b.
// R3: gather kernels restructured to half-wave-per-row float4 (1 KB/wave-instr) + unroll-4.

__global__ __launch_bounds__(256) void zero_i32(int* __restrict__ p, int n) {
    int i = blockIdx.x * blockDim.x + threadIdx.x;
    if (i < n) p[i] = 0;
}

__global__ __launch_bounds__(256) void hist_kernel(const int* __restrict__ dst,
                                                   int* __restrict__ counts, int E) {
    int e = blockIdx.x * blockDim.x + threadIdx.x;
    if (e < E) atomicAdd(&counts[dst[e]], 1);
}

// --- hierarchical exclusive scan over counts[N] ---

__global__ __launch_bounds__(256) void scan_block_sums(const int* __restrict__ counts,
                                                       int* __restrict__ blk_sums, int N) {
    __shared__ int s[256];
    int t = threadIdx.x;
    int i = blockIdx.x * 256 + t;
    s[t] = (i < N) ? counts[i] : 0;
    __syncthreads();
#pragma unroll
    for (int off = 128; off > 0; off >>= 1) {
        if (t < off) s[t] += s[t + off];
        __syncthreads();
    }
    if (t == 0) blk_sums[blockIdx.x] = s[0];
}

__global__ __launch_bounds__(256) void scan_offsets(int* __restrict__ blk_sums, int B) {
    __shared__ int s[2][256];
    int t = threadIdx.x;
    int v = (t < B) ? blk_sums[t] : 0;
    int cur = 0;
    s[0][t] = v;
    __syncthreads();
#pragma unroll
    for (int off = 1; off < 256; off <<= 1) {
        int nxt = cur ^ 1;
        int val = s[cur][t];
        if (t >= off) val += s[cur][t - off];
        s[nxt][t] = val;
        __syncthreads();
        cur = nxt;
    }
    if (t < B) blk_sums[t] = s[cur][t] - v;  // exclusive
}

__global__ __launch_bounds__(256) void scan_final(const int* __restrict__ counts,
                                                  const int* __restrict__ blk_off,
                                                  int* __restrict__ row_ptr,
                                                  int* __restrict__ cursor,
                                                  float* __restrict__ dinv, int N) {
    __shared__ int s[2][256];
    int t = threadIdx.x;
    int i = blockIdx.x * 256 + t;
    int c = (i < N) ? counts[i] : 0;
    int cur = 0;
    s[0][t] = c;
    __syncthreads();
#pragma unroll
    for (int off = 1; off < 256; off <<= 1) {
        int nxt = cur ^ 1;
        int val = s[cur][t];
        if (t >= off) val += s[cur][t - off];
        s[nxt][t] = val;
        __syncthreads();
        cur = nxt;
    }
    if (i < N) {
        int inc = s[cur][t] + blk_off[blockIdx.x];
        int exc = inc - c;
        row_ptr[i] = exc;
        cursor[i] = exc;
        dinv[i] = rsqrtf((float)(c + 1));  // +1 self-loop
        if (i == N - 1) row_ptr[N] = inc;
    }
}

__global__ __launch_bounds__(256) void fill_kernel(const int* __restrict__ src,
                                                   const int* __restrict__ dst,
                                                   int* __restrict__ cursor,
                                                   int* __restrict__ srcs_sorted, int E) {
    int e = blockIdx.x * blockDim.x + threadIdx.x;
    if (e < E) {
        int pos = atomicAdd(&cursor[dst[e]], 1);
        srcs_sorted[pos] = src[e];
    }
}

// H[r][c] = dinv[r] * sum_k X[r][k]*W[k][c].  W (128x128 fp32, 64 KB) staged in LDS.
__global__ __launch_bounds__(256) void gemm_scale_kernel(const float* __restrict__ X,
                                                         const float* __restrict__ W,
                                                         const float* __restrict__ dinv,
                                                         float* __restrict__ H, int N) {
    __shared__ float Ws[128 * 128];
    float4* Ws4 = (float4*)Ws;
    const float4* W4 = (const float4*)W;
    for (int i = threadIdx.x; i < 128 * 32; i += 256) Ws4[i] = W4[i];
    __syncthreads();

    int tx = threadIdx.x & 15;
    int ty = threadIdx.x >> 4;
    int r0 = blockIdx.x * 64 + ty * 4;
    const float4* X4 = (const float4*)X;

    int rr[4];
#pragma unroll
    for (int i = 0; i < 4; ++i) rr[i] = min(r0 + i, N - 1);

    float4 acc[4][2];
#pragma unroll
    for (int i = 0; i < 4; ++i) {
        acc[i][0] = make_float4(0.f, 0.f, 0.f, 0.f);
        acc[i][1] = make_float4(0.f, 0.f, 0.f, 0.f);
    }

    float4 a_cur[4];
#pragma unroll
    for (int i = 0; i < 4; ++i) a_cur[i] = X4[rr[i] * 32];

    for (int kk = 0; kk < 128; kk += 4) {
        float4 a_nxt[4];
        bool more = (kk + 4 < 128);
        if (more) {
#pragma unroll
            for (int i = 0; i < 4; ++i) a_nxt[i] = X4[rr[i] * 32 + (kk >> 2) + 1];
        }
#pragma unroll
        for (int kin = 0; kin < 4; ++kin) {
            float4 w0 = Ws4[(kk + kin) * 32 + 2 * tx];
            float4 w1 = Ws4[(kk + kin) * 32 + 2 * tx + 1];
#pragma unroll
            for (int i = 0; i < 4; ++i) {
                float a = (kin == 0) ? a_cur[i].x : (kin == 1) ? a_cur[i].y
                        : (kin == 2) ? a_cur[i].z : a_cur[i].w;
                acc[i][0].x += a * w0.x; acc[i][0].y += a * w0.y;
                acc[i][0].z += a * w0.z; acc[i][0].w += a * w0.w;
                acc[i][1].x += a * w1.x; acc[i][1].y += a * w1.y;
                acc[i][1].z += a * w1.z; acc[i][1].w += a * w1.w;
            }
        }
        if (more) {
#pragma unroll
            for (int i = 0; i < 4; ++i) a_cur[i] = a_nxt[i];
        }
    }

    float4* H4 = (float4*)H;
#pragma unroll
    for (int i = 0; i < 4; ++i) {
        int r = r0 + i;
        if (r < N) {
            float di = dinv[r];
            float4 o0 = acc[i][0], o1 = acc[i][1];
            o0.x *= di; o0.y *= di; o0.z *= di; o0.w *= di;
            o1.x *= di; o1.y *= di; o1.z *= di; o1.w *= di;
            H4[r * 32 + 2 * tx] = o0;
            H4[r * 32 + 2 * tx + 1] = o1;
        }
    }
}

// Half-wave (32 lanes) per node; lane holds 4 cols as float4 -> one 512 B row per
// half-wave, 1 KB per wave load instruction. Edge loop unrolled 4x, 2 accumulators.
__global__ __launch_bounds__(256) void agg_kernel(const float* __restrict__ Hp,
                                                  const int* __restrict__ row_ptr,
                                                  const int* __restrict__ srcs,
                                                  const float* __restrict__ dinv,
                                                  const float* __restrict__ bias,
                                                  float* __restrict__ Z, int N, int do_relu) {
    int gw = (int)((blockIdx.x * blockDim.x + threadIdx.x) >> 6);  // wave id
    int lane = threadIdx.x & 63;
    int half = lane >> 5;
    int hl = lane & 31;
    int n = gw * 2 + half;
    if (n >= N) return;

    const float4* H4 = (const float4*)Hp;
    float4 acc = H4[(size_t)n * 32 + hl];  // self-loop term
    float4 acc2 = make_float4(0.f, 0.f, 0.f, 0.f);

    int j = row_ptr[n], end = row_ptr[n + 1];
    for (; j + 3 < end; j += 4) {
        int s0 = srcs[j], s1 = srcs[j + 1], s2 = srcs[j + 2], s3 = srcs[j + 3];
        float4 t0 = H4[(size_t)s0 * 32 + hl];
        float4 t1 = H4[(size_t)s1 * 32 + hl];
        float4 t2 = H4[(size_t)s2 * 32 + hl];
        float4 t3 = H4[(size_t)s3 * 32 + hl];
        acc.x += t0.x; acc.y += t0.y; acc.z += t0.z; acc.w += t0.w;
        acc2.x += t1.x; acc2.y += t1.y; acc2.z += t1.z; acc2.w += t1.w;
        acc.x += t2.x; acc.y += t2.y; acc.z += t2.z; acc.w += t2.w;
        acc2.x += t3.x; acc2.y += t3.y; acc2.z += t3.z; acc2.w += t3.w;
    }
    for (; j < end; ++j) {
        int s = srcs[j];
        float4 t = H4[(size_t)s * 32 + hl];
        acc.x += t.x; acc.y += t.y; acc.z += t.z; acc.w += t.w;
    }
    acc.x += acc2.x; acc.y += acc2.y; acc.z += acc2.z; acc.w += acc2.w;

    float di = dinv[n];
    float4 bv = ((const float4*)bias)[hl];
    float4 o;
    o.x = di * acc.x + bv.x;
    o.y = di * acc.y + bv.y;
    o.z = di * acc.z + bv.z;
    o.w = di * acc.w + bv.w;
    if (do_relu) {
        o.x = fmaxf(o.x, 0.f); o.y = fmaxf(o.y, 0.f);
        o.z = fmaxf(o.z, 0.f); o.w = fmaxf(o.w, 0.f);
    }
    ((float4*)Z)[(size_t)n * 32 + hl] = o;
}

// Half-wave per pair: out[p] = dot(z2[a], z2[b]); lane holds 4 cols as float4.
__global__ __launch_bounds__(256) void decode_kernel(const float* __restrict__ Z,
                                                     const int* __restrict__ pa,
                                                     const int* __restrict__ pb,
                                                     float* __restrict__ out, int P) {
    int gw = (int)((blockIdx.x * blockDim.x + threadIdx.x) >> 6);
    int lane = threadIdx.x & 63;
    int half = lane >> 5;
    int hl = lane & 31;
    int p = gw * 2 + half;
    if (p >= P) return;
    int a = pa[p], b = pb[p];
    const float4* Z4 = (const float4*)Z;
    float4 va = Z4[(size_t)a * 32 + hl];
    float4 vb = Z4[(size_t)b * 32 + hl];
    float v = va.x * vb.x + va.y * vb.y + va.z * vb.z + va.w * vb.w;
#pragma unroll
    for (int off = 16; off > 0; off >>= 1) v += __shfl_down(v, off, 32);
    if (hl == 0) out[p] = v;
}

extern "C" void kernel_launch(void* const* d_in, const int* in_sizes, int n_in,
                              void* d_out, int out_size, void* d_ws, size_t ws_size,
                              hipStream_t stream) {
    const int*   edge_index = (const int*)d_in[0];
    const int*   edge_pairs = (const int*)d_in[1];
    const float* emb        = (const float*)d_in[2];
    const float* W1         = (const float*)d_in[3];
    const float* b1         = (const float*)d_in[4];
    const float* W2         = (const float*)d_in[5];
    const float* b2         = (const float*)d_in[6];
    float* out = (float*)d_out;

    int E = in_sizes[0] / 2;
    int P = in_sizes[1] / 2;
    int N = in_sizes[2] / 128;
    int B = (N + 255) / 256;  // scan blocks (196 for N=50000, must be <= 256)

    const int* src = edge_index;
    const int* dst = edge_index + E;
    const int* pa  = edge_pairs;
    const int* pb  = edge_pairs + P;

    char* ws = (char*)d_ws;
    size_t off = 0;
    auto alloc = [&](size_t bytes) -> void* {
        void* p = ws + off;
        off = (off + bytes + 255) & ~(size_t)255;
        return p;
    };
    float* bufA        = (float*)alloc((size_t)N * 128 * sizeof(float)); // h'
    float* bufB        = (float*)alloc((size_t)N * 128 * sizeof(float)); // z
    int*   srcs_sorted = (int*)alloc((size_t)E * sizeof(int));
    int*   row_ptr     = (int*)alloc((size_t)(N + 1) * sizeof(int));
    int*   counts      = (int*)alloc((size_t)N * sizeof(int));           // counts -> cursor
    float* dinv        = (float*)alloc((size_t)N * sizeof(float));
    int*   blk_sums    = (int*)alloc((size_t)B * sizeof(int));

    // CSR build
    zero_i32<<<(N + 255) / 256, 256, 0, stream>>>(counts, N);
    hist_kernel<<<(E + 255) / 256, 256, 0, stream>>>(dst, counts, E);
    scan_block_sums<<<B, 256, 0, stream>>>(counts, blk_sums, N);
    scan_offsets<<<1, 256, 0, stream>>>(blk_sums, B);
    scan_final<<<B, 256, 0, stream>>>(counts, blk_sums, row_ptr, counts, dinv, N);
    fill_kernel<<<(E + 255) / 256, 256, 0, stream>>>(src, dst, counts, srcs_sorted, E);

    // Layer 1: h1' = dinv*(emb@W1) -> agg+b1+relu -> z1 (bufB)
    gemm_scale_kernel<<<(N + 63) / 64, 256, 0, stream>>>(emb, W1, dinv, bufA, N);
    agg_kernel<<<(N + 7) / 8, 256, 0, stream>>>(bufA, row_ptr, srcs_sorted, dinv, b1, bufB, N, 1);

    // Layer 2: h2' = dinv*(z1@W2) -> agg+b2 -> z2 (bufB)
    gemm_scale_kernel<<<(N + 63) / 64, 256, 0, stream>>>(bufB, W2, dinv, bufA, N);
    agg_kernel<<<(N + 7) / 8, 256, 0, stream>>>(bufA, row_ptr, srcs_sorted, dinv, b2, bufB, N, 0);

    // Decode
    decode_kernel<<<(P + 7) / 8, 256, 0, stream>>>(bufB, pa, pb, out, P);
}

// Round 4
// 361.008 us; speedup vs baseline: 1.7633x; 1.1579x over previous
//
#include <hip/hip_runtime.h>

// GCN link predictor. fp32 math, bf16 intermediate node-feature buffers (R4).
// Pipeline: CSR build (hist -> hierarchical scan -> fill) -> [GEMM+dinv-scale -> CSR gather-agg]x2
//           -> pair-dot decode.
// norm factorization: h'[i] = dinv[i]*(x@W)[i];  z[i] = dinv[i]*(h'[i] + sum_{src->i} h'[src]) + b.
// R3: gathers = half-wave-per-row + unroll-4 (90->59us).  R4: intermediates bf16 (halve
// beyond-L2 bytes; agg was at 3.2 TB/s L2-miss BW, VALU 12% -> bandwidth-bound).

__device__ __forceinline__ unsigned short f2bf(float f) {
    union { float f; unsigned int u; } v; v.f = f;
    unsigned int u = v.u;
    u += 0x7fffu + ((u >> 16) & 1u);   // round-to-nearest-even
    return (unsigned short)(u >> 16);
}

__device__ __forceinline__ unsigned int pack2(float a, float b) {
    return (unsigned int)f2bf(a) | ((unsigned int)f2bf(b) << 16);
}

__device__ __forceinline__ float4 cvt4(uint2 u) {
    float4 f;
    f.x = __uint_as_float(u.x << 16);
    f.y = __uint_as_float(u.x & 0xffff0000u);
    f.z = __uint_as_float(u.y << 16);
    f.w = __uint_as_float(u.y & 0xffff0000u);
    return f;
}

__global__ __launch_bounds__(256) void zero_i32(int* __restrict__ p, int n) {
    int i = blockIdx.x * blockDim.x + threadIdx.x;
    if (i < n) p[i] = 0;
}

__global__ __launch_bounds__(256) void hist_kernel(const int* __restrict__ dst,
                                                   int* __restrict__ counts, int E) {
    int e = blockIdx.x * blockDim.x + threadIdx.x;
    if (e < E) atomicAdd(&counts[dst[e]], 1);
}

// --- hierarchical exclusive scan over counts[N] ---

__global__ __launch_bounds__(256) void scan_block_sums(const int* __restrict__ counts,
                                                       int* __restrict__ blk_sums, int N) {
    __shared__ int s[256];
    int t = threadIdx.x;
    int i = blockIdx.x * 256 + t;
    s[t] = (i < N) ? counts[i] : 0;
    __syncthreads();
#pragma unroll
    for (int off = 128; off > 0; off >>= 1) {
        if (t < off) s[t] += s[t + off];
        __syncthreads();
    }
    if (t == 0) blk_sums[blockIdx.x] = s[0];
}

__global__ __launch_bounds__(256) void scan_offsets(int* __restrict__ blk_sums, int B) {
    __shared__ int s[2][256];
    int t = threadIdx.x;
    int v = (t < B) ? blk_sums[t] : 0;
    int cur = 0;
    s[0][t] = v;
    __syncthreads();
#pragma unroll
    for (int off = 1; off < 256; off <<= 1) {
        int nxt = cur ^ 1;
        int val = s[cur][t];
        if (t >= off) val += s[cur][t - off];
        s[nxt][t] = val;
        __syncthreads();
        cur = nxt;
    }
    if (t < B) blk_sums[t] = s[cur][t] - v;  // exclusive
}

__global__ __launch_bounds__(256) void scan_final(const int* __restrict__ counts,
                                                  const int* __restrict__ blk_off,
                                                  int* __restrict__ row_ptr,
                                                  int* __restrict__ cursor,
                                                  float* __restrict__ dinv, int N) {
    __shared__ int s[2][256];
    int t = threadIdx.x;
    int i = blockIdx.x * 256 + t;
    int c = (i < N) ? counts[i] : 0;
    int cur = 0;
    s[0][t] = c;
    __syncthreads();
#pragma unroll
    for (int off = 1; off < 256; off <<= 1) {
        int nxt = cur ^ 1;
        int val = s[cur][t];
        if (t >= off) val += s[cur][t - off];
        s[nxt][t] = val;
        __syncthreads();
        cur = nxt;
    }
    if (i < N) {
        int inc = s[cur][t] + blk_off[blockIdx.x];
        int exc = inc - c;
        row_ptr[i] = exc;
        cursor[i] = exc;
        dinv[i] = rsqrtf((float)(c + 1));  // +1 self-loop
        if (i == N - 1) row_ptr[N] = inc;
    }
}

__global__ __launch_bounds__(256) void fill_kernel(const int* __restrict__ src,
                                                   const int* __restrict__ dst,
                                                   int* __restrict__ cursor,
                                                   int* __restrict__ srcs_sorted, int E) {
    int e = blockIdx.x * blockDim.x + threadIdx.x;
    if (e < E) {
        int pos = atomicAdd(&cursor[dst[e]], 1);
        srcs_sorted[pos] = src[e];
    }
}

// H[r][c] = dinv[r] * sum_k X[r][k]*W[k][c], stored bf16.  W (128x128 fp32) in LDS.
// X input is fp32 (layer 1) or bf16 (layer 2) per template param.
// Block: 256 threads = 16 (tx: 8 cols) x 16 (ty: 4 rows) -> 64-row tile.
template <bool BF16IN>
__global__ __launch_bounds__(256) void gemm_scale_kernel(const void* __restrict__ Xv,
                                                         const float* __restrict__ W,
                                                         const float* __restrict__ dinv,
                                                         uint4* __restrict__ H, int N) {
    __shared__ float Ws[128 * 128];
    float4* Ws4 = (float4*)Ws;
    const float4* W4 = (const float4*)W;
    for (int i = threadIdx.x; i < 128 * 32; i += 256) Ws4[i] = W4[i];
    __syncthreads();

    int tx = threadIdx.x & 15;
    int ty = threadIdx.x >> 4;
    int r0 = blockIdx.x * 64 + ty * 4;

    auto loadA = [&](int r, int k4) -> float4 {
        if constexpr (BF16IN) {
            uint2 u = ((const uint2*)Xv)[r * 32 + k4];
            return cvt4(u);
        } else {
            return ((const float4*)Xv)[r * 32 + k4];
        }
    };

    int rr[4];
#pragma unroll
    for (int i = 0; i < 4; ++i) rr[i] = min(r0 + i, N - 1);

    float4 acc[4][2];
#pragma unroll
    for (int i = 0; i < 4; ++i) {
        acc[i][0] = make_float4(0.f, 0.f, 0.f, 0.f);
        acc[i][1] = make_float4(0.f, 0.f, 0.f, 0.f);
    }

    float4 a_cur[4];
#pragma unroll
    for (int i = 0; i < 4; ++i) a_cur[i] = loadA(rr[i], 0);

    for (int kk = 0; kk < 128; kk += 4) {
        float4 a_nxt[4];
        bool more = (kk + 4 < 128);
        if (more) {
#pragma unroll
            for (int i = 0; i < 4; ++i) a_nxt[i] = loadA(rr[i], (kk >> 2) + 1);
        }
#pragma unroll
        for (int kin = 0; kin < 4; ++kin) {
            float4 w0 = Ws4[(kk + kin) * 32 + 2 * tx];
            float4 w1 = Ws4[(kk + kin) * 32 + 2 * tx + 1];
#pragma unroll
            for (int i = 0; i < 4; ++i) {
                float a = (kin == 0) ? a_cur[i].x : (kin == 1) ? a_cur[i].y
                        : (kin == 2) ? a_cur[i].z : a_cur[i].w;
                acc[i][0].x += a * w0.x; acc[i][0].y += a * w0.y;
                acc[i][0].z += a * w0.z; acc[i][0].w += a * w0.w;
                acc[i][1].x += a * w1.x; acc[i][1].y += a * w1.y;
                acc[i][1].z += a * w1.z; acc[i][1].w += a * w1.w;
            }
        }
        if (more) {
#pragma unroll
            for (int i = 0; i < 4; ++i) a_cur[i] = a_nxt[i];
        }
    }

#pragma unroll
    for (int i = 0; i < 4; ++i) {
        int r = r0 + i;
        if (r < N) {
            float di = dinv[r];
            float4 o0 = acc[i][0], o1 = acc[i][1];
            o0.x *= di; o0.y *= di; o0.z *= di; o0.w *= di;
            o1.x *= di; o1.y *= di; o1.z *= di; o1.w *= di;
            uint4 o;
            o.x = pack2(o0.x, o0.y);
            o.y = pack2(o0.z, o0.w);
            o.z = pack2(o1.x, o1.y);
            o.w = pack2(o1.z, o1.w);
            H[r * 16 + tx] = o;  // cols 8*tx .. 8*tx+7
        }
    }
}

// Half-wave (32 lanes) per node; lane holds 4 cols as bf16x4 (uint2) -> one 256 B row
// per half-wave. fp32 accumulate. Edge loop unrolled 4x, 2 accumulators.
__global__ __launch_bounds__(256) void agg_kernel(const unsigned short* __restrict__ Hp,
                                                  const int* __restrict__ row_ptr,
                                                  const int* __restrict__ srcs,
                                                  const float* __restrict__ dinv,
                                                  const float* __restrict__ bias,
                                                  unsigned short* __restrict__ Z,
                                                  int N, int do_relu) {
    int gw = (int)((blockIdx.x * blockDim.x + threadIdx.x) >> 6);  // wave id
    int lane = threadIdx.x & 63;
    int half = lane >> 5;
    int hl = lane & 31;
    int n = gw * 2 + half;
    if (n >= N) return;

    const uint2* H2 = (const uint2*)Hp;
    float4 acc = cvt4(H2[(size_t)n * 32 + hl]);  // self-loop term
    float4 acc2 = make_float4(0.f, 0.f, 0.f, 0.f);

    int j = row_ptr[n], end = row_ptr[n + 1];
    for (; j + 3 < end; j += 4) {
        int s0 = srcs[j], s1 = srcs[j + 1], s2 = srcs[j + 2], s3 = srcs[j + 3];
        float4 t0 = cvt4(H2[(size_t)s0 * 32 + hl]);
        float4 t1 = cvt4(H2[(size_t)s1 * 32 + hl]);
        float4 t2 = cvt4(H2[(size_t)s2 * 32 + hl]);
        float4 t3 = cvt4(H2[(size_t)s3 * 32 + hl]);
        acc.x += t0.x; acc.y += t0.y; acc.z += t0.z; acc.w += t0.w;
        acc2.x += t1.x; acc2.y += t1.y; acc2.z += t1.z; acc2.w += t1.w;
        acc.x += t2.x; acc.y += t2.y; acc.z += t2.z; acc.w += t2.w;
        acc2.x += t3.x; acc2.y += t3.y; acc2.z += t3.z; acc2.w += t3.w;
    }
    for (; j < end; ++j) {
        int s = srcs[j];
        float4 t = cvt4(H2[(size_t)s * 32 + hl]);
        acc.x += t.x; acc.y += t.y; acc.z += t.z; acc.w += t.w;
    }
    acc.x += acc2.x; acc.y += acc2.y; acc.z += acc2.z; acc.w += acc2.w;

    float di = dinv[n];
    float4 bv = ((const float4*)bias)[hl];  // cols 4*hl .. 4*hl+3
    float ox = di * acc.x + bv.x;
    float oy = di * acc.y + bv.y;
    float oz = di * acc.z + bv.z;
    float ow = di * acc.w + bv.w;
    if (do_relu) {
        ox = fmaxf(ox, 0.f); oy = fmaxf(oy, 0.f);
        oz = fmaxf(oz, 0.f); ow = fmaxf(ow, 0.f);
    }
    uint2 o;
    o.x = pack2(ox, oy);
    o.y = pack2(oz, ow);
    ((uint2*)Z)[(size_t)n * 32 + hl] = o;
}

// Half-wave per pair: out[p] = dot(z2[a], z2[b]); lane holds 4 cols (bf16x4).
__global__ __launch_bounds__(256) void decode_kernel(const unsigned short* __restrict__ Z,
                                                     const int* __restrict__ pa,
                                                     const int* __restrict__ pb,
                                                     float* __restrict__ out, int P) {
    int gw = (int)((blockIdx.x * blockDim.x + threadIdx.x) >> 6);
    int lane = threadIdx.x & 63;
    int half = lane >> 5;
    int hl = lane & 31;
    int p = gw * 2 + half;
    if (p >= P) return;
    int a = pa[p], b = pb[p];
    const uint2* Z2 = (const uint2*)Z;
    float4 va = cvt4(Z2[(size_t)a * 32 + hl]);
    float4 vb = cvt4(Z2[(size_t)b * 32 + hl]);
    float v = va.x * vb.x + va.y * vb.y + va.z * vb.z + va.w * vb.w;
#pragma unroll
    for (int off = 16; off > 0; off >>= 1) v += __shfl_down(v, off, 32);
    if (hl == 0) out[p] = v;
}

extern "C" void kernel_launch(void* const* d_in, const int* in_sizes, int n_in,
                              void* d_out, int out_size, void* d_ws, size_t ws_size,
                              hipStream_t stream) {
    const int*   edge_index = (const int*)d_in[0];
    const int*   edge_pairs = (const int*)d_in[1];
    const float* emb        = (const float*)d_in[2];
    const float* W1         = (const float*)d_in[3];
    const float* b1         = (const float*)d_in[4];
    const float* W2         = (const float*)d_in[5];
    const float* b2         = (const float*)d_in[6];
    float* out = (float*)d_out;

    int E = in_sizes[0] / 2;
    int P = in_sizes[1] / 2;
    int N = in_sizes[2] / 128;
    int B = (N + 255) / 256;  // scan blocks (196 for N=50000, must be <= 256)

    const int* src = edge_index;
    const int* dst = edge_index + E;
    const int* pa  = edge_pairs;
    const int* pb  = edge_pairs + P;

    char* ws = (char*)d_ws;
    size_t off = 0;
    auto alloc = [&](size_t bytes) -> void* {
        void* p = ws + off;
        off = (off + bytes + 255) & ~(size_t)255;
        return p;
    };
    unsigned short* bufA = (unsigned short*)alloc((size_t)N * 128 * 2); // h' (bf16)
    unsigned short* bufB = (unsigned short*)alloc((size_t)N * 128 * 2); // z  (bf16)
    int*   srcs_sorted = (int*)alloc((size_t)E * sizeof(int));
    int*   row_ptr     = (int*)alloc((size_t)(N + 1) * sizeof(int));
    int*   counts      = (int*)alloc((size_t)N * sizeof(int));          // counts -> cursor
    float* dinv        = (float*)alloc((size_t)N * sizeof(float));
    int*   blk_sums    = (int*)alloc((size_t)B * sizeof(int));

    // CSR build
    zero_i32<<<(N + 255) / 256, 256, 0, stream>>>(counts, N);
    hist_kernel<<<(E + 255) / 256, 256, 0, stream>>>(dst, counts, E);
    scan_block_sums<<<B, 256, 0, stream>>>(counts, blk_sums, N);
    scan_offsets<<<1, 256, 0, stream>>>(blk_sums, B);
    scan_final<<<B, 256, 0, stream>>>(counts, blk_sums, row_ptr, counts, dinv, N);
    fill_kernel<<<(E + 255) / 256, 256, 0, stream>>>(src, dst, counts, srcs_sorted, E);

    // Layer 1: h1' = dinv*(emb@W1) -> agg+b1+relu -> z1 (bufB)
    gemm_scale_kernel<false><<<(N + 63) / 64, 256, 0, stream>>>(emb, W1, dinv, (uint4*)bufA, N);
    agg_kernel<<<(N + 7) / 8, 256, 0, stream>>>(bufA, row_ptr, srcs_sorted, dinv, b1, bufB, N, 1);

    // Layer 2: h2' = dinv*(z1@W2) -> agg+b2 -> z2 (bufB)
    gemm_scale_kernel<true><<<(N + 63) / 64, 256, 0, stream>>>(bufB, W2, dinv, (uint4*)bufA, N);
    agg_kernel<<<(N + 7) / 8, 256, 0, stream>>>(bufA, row_ptr, srcs_sorted, dinv, b2, bufB, N, 0);

    // Decode
    decode_kernel<<<(P + 7) / 8, 256, 0, stream>>>(bufB, pa, pb, out, P);
}

// Round 5
// 317.503 us; speedup vs baseline: 2.0049x; 1.1370x over previous
//
#include <hip/hip_runtime.h>

// GCN link predictor. fp32 math, bf16 intermediates + bf16 MFMA GEMM (R5).
// Pipeline: CSR build (hist -> hierarchical scan -> fill) -> [MFMA GEMM+dinv-scale -> gather-agg]x2
//           -> pair-dot decode.
// norm factorization: h'[i] = dinv[i]*(x@W)[i];  z[i] = dinv[i]*(h'[i] + sum_{src->i} h'[src]) + b.
// R3: gathers half-wave float4 (90->59us). R4: bf16 intermediates (agg 59->~35us).
// R5: GEMM on matrix cores (was 30 TF VALU-bound w/ 3.2M LDS bank conflicts, 55us each).

typedef __attribute__((ext_vector_type(8))) short short8;   // 8 bf16 (A/B frag)
typedef __attribute__((ext_vector_type(4))) float floatx4;  // C/D frag

__device__ __forceinline__ unsigned short f2bf(float f) {
    union { float f; unsigned int u; } v; v.f = f;
    unsigned int u = v.u;
    u += 0x7fffu + ((u >> 16) & 1u);   // round-to-nearest-even
    return (unsigned short)(u >> 16);
}

__device__ __forceinline__ unsigned int pack2(float a, float b) {
    return (unsigned int)f2bf(a) | ((unsigned int)f2bf(b) << 16);
}

__device__ __forceinline__ float4 cvt4(uint2 u) {
    float4 f;
    f.x = __uint_as_float(u.x << 16);
    f.y = __uint_as_float(u.x & 0xffff0000u);
    f.z = __uint_as_float(u.y << 16);
    f.w = __uint_as_float(u.y & 0xffff0000u);
    return f;
}

__global__ __launch_bounds__(256) void zero_i32(int* __restrict__ p, int n) {
    int i = blockIdx.x * blockDim.x + threadIdx.x;
    if (i < n) p[i] = 0;
}

__global__ __launch_bounds__(256) void hist_kernel(const int* __restrict__ dst,
                                                   int* __restrict__ counts, int E) {
    int e = blockIdx.x * blockDim.x + threadIdx.x;
    if (e < E) atomicAdd(&counts[dst[e]], 1);
}

// --- hierarchical exclusive scan over counts[N] ---

__global__ __launch_bounds__(256) void scan_block_sums(const int* __restrict__ counts,
                                                       int* __restrict__ blk_sums, int N) {
    __shared__ int s[256];
    int t = threadIdx.x;
    int i = blockIdx.x * 256 + t;
    s[t] = (i < N) ? counts[i] : 0;
    __syncthreads();
#pragma unroll
    for (int off = 128; off > 0; off >>= 1) {
        if (t < off) s[t] += s[t + off];
        __syncthreads();
    }
    if (t == 0) blk_sums[blockIdx.x] = s[0];
}

__global__ __launch_bounds__(256) void scan_offsets(int* __restrict__ blk_sums, int B) {
    __shared__ int s[2][256];
    int t = threadIdx.x;
    int v = (t < B) ? blk_sums[t] : 0;
    int cur = 0;
    s[0][t] = v;
    __syncthreads();
#pragma unroll
    for (int off = 1; off < 256; off <<= 1) {
        int nxt = cur ^ 1;
        int val = s[cur][t];
        if (t >= off) val += s[cur][t - off];
        s[nxt][t] = val;
        __syncthreads();
        cur = nxt;
    }
    if (t < B) blk_sums[t] = s[cur][t] - v;  // exclusive
}

__global__ __launch_bounds__(256) void scan_final(const int* __restrict__ counts,
                                                  const int* __restrict__ blk_off,
                                                  int* __restrict__ row_ptr,
                                                  int* __restrict__ cursor,
                                                  float* __restrict__ dinv, int N) {
    __shared__ int s[2][256];
    int t = threadIdx.x;
    int i = blockIdx.x * 256 + t;
    int c = (i < N) ? counts[i] : 0;
    int cur = 0;
    s[0][t] = c;
    __syncthreads();
#pragma unroll
    for (int off = 1; off < 256; off <<= 1) {
        int nxt = cur ^ 1;
        int val = s[cur][t];
        if (t >= off) val += s[cur][t - off];
        s[nxt][t] = val;
        __syncthreads();
        cur = nxt;
    }
    if (i < N) {
        int inc = s[cur][t] + blk_off[blockIdx.x];
        int exc = inc - c;
        row_ptr[i] = exc;
        cursor[i] = exc;
        dinv[i] = rsqrtf((float)(c + 1));  // +1 self-loop
        if (i == N - 1) row_ptr[N] = inc;
    }
}

__global__ __launch_bounds__(256) void fill_kernel(const int* __restrict__ src,
                                                   const int* __restrict__ dst,
                                                   int* __restrict__ cursor,
                                                   int* __restrict__ srcs_sorted, int E) {
    int e = blockIdx.x * blockDim.x + threadIdx.x;
    if (e < E) {
        int pos = atomicAdd(&cursor[dst[e]], 1);
        srcs_sorted[pos] = src[e];
    }
}

// MFMA GEMM: H[r][c] = bf16( dinv[r] * sum_k X[r][k]*W[k][c] ), 64 rows x 128 cols per block.
// 4 waves; wave w computes rows 16w..16w+15 x all 128 cols = 8 n-tiles of 16x16x32 MFMA.
// LDS: WB = W in B-frag layout (bf16, 32 KB), XL = X-tile row-major bf16 padded (17 KB);
// epilogue reuses LDS as fp32 C-tile for coalesced packed stores.
template <bool BF16IN>
__global__ __launch_bounds__(256) void gemm_mfma_kernel(const void* __restrict__ Xv,
                                                        const float* __restrict__ W,
                                                        const float* __restrict__ dinv,
                                                        uint2* __restrict__ H, int N) {
    __shared__ __align__(16) char smem[50176];
    short* WB = (short*)smem;            // [nt][kt][lane][j] : ((nt*4+kt)*64+lane)*8+j
    short* XL = (short*)(smem + 32768);  // [row][k], row stride 136 shorts (272 B, 16B-aligned)
    float* Cst = (float*)smem;           // epilogue overlap: [row][col], stride 132 floats

    const int tid = threadIdx.x;
    const int w = tid >> 6;
    const int lane = tid & 63;
    const int blk = blockIdx.x;

    // --- stage W (128x128 fp32) -> WB (bf16 B-frag layout) ---
    {
        const float4* W4 = (const float4*)W;
#pragma unroll
        for (int i = 0; i < 16; ++i) {
            int f = tid + i * 256;          // float4 slot: k = f>>5, c4 = f&31
            int k = f >> 5;
            int c4 = f & 31;
            float4 wv = W4[f];
            int kt = k >> 5, q = (k >> 3) & 3, j = k & 7;
            float e[4] = {wv.x, wv.y, wv.z, wv.w};
#pragma unroll
            for (int m = 0; m < 4; ++m) {
                int c = c4 * 4 + m;
                int nt = c >> 4;
                int ln = q * 16 + (c & 15);
                WB[((nt * 4 + kt) * 64 + ln) * 8 + j] = (short)f2bf(e[m]);
            }
        }
    }

    // --- stage X tile (64 rows) -> XL bf16 row-major ---
    {
#pragma unroll
        for (int i = 0; i < 8; ++i) {
            int f = tid + i * 256;          // slot: row = f>>5, c4 = f&31 (4 elems)
            int row = f >> 5;
            int c4 = f & 31;
            int gr = min(blk * 64 + row, N - 1);
            uint2 u;
            if constexpr (BF16IN) {
                u = ((const uint2*)Xv)[(size_t)gr * 32 + c4];
            } else {
                float4 xv = ((const float4*)Xv)[(size_t)gr * 32 + c4];
                u.x = pack2(xv.x, xv.y);
                u.y = pack2(xv.z, xv.w);
            }
            *(uint2*)&XL[row * 136 + c4 * 4] = u;
        }
    }
    __syncthreads();

    // --- MFMA main: a-frags (4 ksteps) + 8 n-tiles ---
    const int arow = w * 16 + (lane & 15);
    const int koff = (lane >> 4) * 8;
    short8 a[4];
#pragma unroll
    for (int kt = 0; kt < 4; ++kt)
        a[kt] = *(const short8*)&XL[arow * 136 + kt * 32 + koff];

    floatx4 acc[8];
#pragma unroll
    for (int nt = 0; nt < 8; ++nt) acc[nt] = (floatx4){0.f, 0.f, 0.f, 0.f};

#pragma unroll
    for (int kt = 0; kt < 4; ++kt) {
#pragma unroll
        for (int nt = 0; nt < 8; ++nt) {
            short8 b = *(const short8*)&WB[((nt * 4 + kt) * 64 + lane) * 8];
            acc[nt] = __builtin_amdgcn_mfma_f32_16x16x32_bf16(a[kt], b, acc[nt], 0, 0, 0);
        }
    }
    __syncthreads();  // all waves done reading WB/XL before overwrite

    // --- epilogue: C frags -> LDS fp32 -> scale+pack -> coalesced global stores ---
    {
        int q = lane >> 4, cn = lane & 15;
#pragma unroll
        for (int nt = 0; nt < 8; ++nt)
#pragma unroll
            for (int r = 0; r < 4; ++r)
                Cst[(w * 16 + q * 4 + r) * 132 + nt * 16 + cn] = acc[nt][r];
    }
    __syncthreads();
    {
#pragma unroll
        for (int i = 0; i < 8; ++i) {
            int f = tid + i * 256;          // slot: row = f>>5, c4 = f&31
            int row = f >> 5;
            int c4 = f & 31;
            int gr = blk * 64 + row;
            if (gr < N) {
                float4 v = *(float4*)&Cst[row * 132 + c4 * 4];
                float di = dinv[gr];
                uint2 o;
                o.x = pack2(v.x * di, v.y * di);
                o.y = pack2(v.z * di, v.w * di);
                H[(size_t)gr * 32 + c4] = o;
            }
        }
    }
}

// Half-wave (32 lanes) per node; lane holds 4 cols as bf16x4 (uint2) -> one 256 B row
// per half-wave. fp32 accumulate. Edge loop unrolled 4x, 2 accumulators.
__global__ __launch_bounds__(256) void agg_kernel(const unsigned short* __restrict__ Hp,
                                                  const int* __restrict__ row_ptr,
                                                  const int* __restrict__ srcs,
                                                  const float* __restrict__ dinv,
                                                  const float* __restrict__ bias,
                                                  unsigned short* __restrict__ Z,
                                                  int N, int do_relu) {
    int gw = (int)((blockIdx.x * blockDim.x + threadIdx.x) >> 6);  // wave id
    int lane = threadIdx.x & 63;
    int half = lane >> 5;
    int hl = lane & 31;
    int n = gw * 2 + half;
    if (n >= N) return;

    const uint2* H2 = (const uint2*)Hp;
    float4 acc = cvt4(H2[(size_t)n * 32 + hl]);  // self-loop term
    float4 acc2 = make_float4(0.f, 0.f, 0.f, 0.f);

    int j = row_ptr[n], end = row_ptr[n + 1];
    for (; j + 3 < end; j += 4) {
        int s0 = srcs[j], s1 = srcs[j + 1], s2 = srcs[j + 2], s3 = srcs[j + 3];
        float4 t0 = cvt4(H2[(size_t)s0 * 32 + hl]);
        float4 t1 = cvt4(H2[(size_t)s1 * 32 + hl]);
        float4 t2 = cvt4(H2[(size_t)s2 * 32 + hl]);
        float4 t3 = cvt4(H2[(size_t)s3 * 32 + hl]);
        acc.x += t0.x; acc.y += t0.y; acc.z += t0.z; acc.w += t0.w;
        acc2.x += t1.x; acc2.y += t1.y; acc2.z += t1.z; acc2.w += t1.w;
        acc.x += t2.x; acc.y += t2.y; acc.z += t2.z; acc.w += t2.w;
        acc2.x += t3.x; acc2.y += t3.y; acc2.z += t3.z; acc2.w += t3.w;
    }
    for (; j < end; ++j) {
        int s = srcs[j];
        float4 t = cvt4(H2[(size_t)s * 32 + hl]);
        acc.x += t.x; acc.y += t.y; acc.z += t.z; acc.w += t.w;
    }
    acc.x += acc2.x; acc.y += acc2.y; acc.z += acc2.z; acc.w += acc2.w;

    float di = dinv[n];
    float4 bv = ((const float4*)bias)[hl];  // cols 4*hl .. 4*hl+3
    float ox = di * acc.x + bv.x;
    float oy = di * acc.y + bv.y;
    float oz = di * acc.z + bv.z;
    float ow = di * acc.w + bv.w;
    if (do_relu) {
        ox = fmaxf(ox, 0.f); oy = fmaxf(oy, 0.f);
        oz = fmaxf(oz, 0.f); ow = fmaxf(ow, 0.f);
    }
    uint2 o;
    o.x = pack2(ox, oy);
    o.y = pack2(oz, ow);
    ((uint2*)Z)[(size_t)n * 32 + hl] = o;
}

// Half-wave per pair: out[p] = dot(z2[a], z2[b]); lane holds 4 cols (bf16x4).
__global__ __launch_bounds__(256) void decode_kernel(const unsigned short* __restrict__ Z,
                                                     const int* __restrict__ pa,
                                                     const int* __restrict__ pb,
                                                     float* __restrict__ out, int P) {
    int gw = (int)((blockIdx.x * blockDim.x + threadIdx.x) >> 6);
    int lane = threadIdx.x & 63;
    int half = lane >> 5;
    int hl = lane & 31;
    int p = gw * 2 + half;
    if (p >= P) return;
    int a = pa[p], b = pb[p];
    const uint2* Z2 = (const uint2*)Z;
    float4 va = cvt4(Z2[(size_t)a * 32 + hl]);
    float4 vb = cvt4(Z2[(size_t)b * 32 + hl]);
    float v = va.x * vb.x + va.y * vb.y + va.z * vb.z + va.w * vb.w;
#pragma unroll
    for (int off = 16; off > 0; off >>= 1) v += __shfl_down(v, off, 32);
    if (hl == 0) out[p] = v;
}

extern "C" void kernel_launch(void* const* d_in, const int* in_sizes, int n_in,
                              void* d_out, int out_size, void* d_ws, size_t ws_size,
                              hipStream_t stream) {
    const int*   edge_index = (const int*)d_in[0];
    const int*   edge_pairs = (const int*)d_in[1];
    const float* emb        = (const float*)d_in[2];
    const float* W1         = (const float*)d_in[3];
    const float* b1         = (const float*)d_in[4];
    const float* W2         = (const float*)d_in[5];
    const float* b2         = (const float*)d_in[6];
    float* out = (float*)d_out;

    int E = in_sizes[0] / 2;
    int P = in_sizes[1] / 2;
    int N = in_sizes[2] / 128;
    int B = (N + 255) / 256;  // scan blocks (196 for N=50000, must be <= 256)

    const int* src = edge_index;
    const int* dst = edge_index + E;
    const int* pa  = edge_pairs;
    const int* pb  = edge_pairs + P;

    char* ws = (char*)d_ws;
    size_t off = 0;
    auto alloc = [&](size_t bytes) -> void* {
        void* p = ws + off;
        off = (off + bytes + 255) & ~(size_t)255;
        return p;
    };
    unsigned short* bufA = (unsigned short*)alloc((size_t)N * 128 * 2); // h' (bf16)
    unsigned short* bufB = (unsigned short*)alloc((size_t)N * 128 * 2); // z  (bf16)
    int*   srcs_sorted = (int*)alloc((size_t)E * sizeof(int));
    int*   row_ptr     = (int*)alloc((size_t)(N + 1) * sizeof(int));
    int*   counts      = (int*)alloc((size_t)N * sizeof(int));          // counts -> cursor
    float* dinv        = (float*)alloc((size_t)N * sizeof(float));
    int*   blk_sums    = (int*)alloc((size_t)B * sizeof(int));

    // CSR build
    zero_i32<<<(N + 255) / 256, 256, 0, stream>>>(counts, N);
    hist_kernel<<<(E + 255) / 256, 256, 0, stream>>>(dst, counts, E);
    scan_block_sums<<<B, 256, 0, stream>>>(counts, blk_sums, N);
    scan_offsets<<<1, 256, 0, stream>>>(blk_sums, B);
    scan_final<<<B, 256, 0, stream>>>(counts, blk_sums, row_ptr, counts, dinv, N);
    fill_kernel<<<(E + 255) / 256, 256, 0, stream>>>(src, dst, counts, srcs_sorted, E);

    // Layer 1: h1' = dinv*(emb@W1) -> agg+b1+relu -> z1 (bufB)
    gemm_mfma_kernel<false><<<(N + 63) / 64, 256, 0, stream>>>(emb, W1, dinv, (uint2*)bufA, N);
    agg_kernel<<<(N + 7) / 8, 256, 0, stream>>>(bufA, row_ptr, srcs_sorted, dinv, b1, bufB, N, 1);

    // Layer 2: h2' = dinv*(z1@W2) -> agg+b2 -> z2 (bufB)
    gemm_mfma_kernel<true><<<(N + 63) / 64, 256, 0, stream>>>(bufB, W2, dinv, (uint2*)bufA, N);
    agg_kernel<<<(N + 7) / 8, 256, 0, stream>>>(bufA, row_ptr, srcs_sorted, dinv, b2, bufB, N, 0);

    // Decode
    decode_kernel<<<(P + 7) / 8, 256, 0, stream>>>(bufB, pa, pb, out, P);
}